// Round 13
// baseline (523.337 us; speedup 1.0000x reference)
//
#include <hip/hip_runtime.h>
#include <hip/hip_bf16.h>

typedef unsigned int uint32;
typedef float floatx2 __attribute__((ext_vector_type(2)));

#define CHUNK 16384

// ============ bucketed CSR build (dst>>8 buckets, LDS-atomic sort) ============

__global__ __launch_bounds__(256) void k_bhist(const int* __restrict__ dst,
                                               int* __restrict__ bcnt,
                                               int E, int NBUCK, int NCH) {
    __shared__ int h[512];
    int c = blockIdx.x, tid = threadIdx.x;
    for (int i = tid; i < NBUCK; i += 256) h[i] = 0;
    __syncthreads();
    int base = c * CHUNK;
#pragma unroll
    for (int k = 0; k < CHUNK / 256; ++k) {
        int e = base + k * 256 + tid;
        if (e < E) atomicAdd(&h[dst[e] >> 8], 1);
    }
    __syncthreads();
    for (int i = tid; i < NBUCK; i += 256) bcnt[(size_t)i * NCH + c] = h[i];
}

__global__ __launch_bounds__(128) void k_bscan1(const int* __restrict__ bcnt,
                                                int* __restrict__ bofs,
                                                int* __restrict__ btot, int NCH) {
    __shared__ int tmp[128];
    int b = blockIdx.x, t = threadIdx.x;
    int v = (t < NCH) ? bcnt[(size_t)b * NCH + t] : 0;
    tmp[t] = v;
    __syncthreads();
    for (int off = 1; off < 128; off <<= 1) {
        int u = (t >= off) ? tmp[t - off] : 0;
        __syncthreads();
        tmp[t] += u;
        __syncthreads();
    }
    if (t < NCH) bofs[(size_t)b * NCH + t] = tmp[t] - v;
    if (t == 127) btot[b] = tmp[127];
}

__global__ __launch_bounds__(512) void k_bscan2(const int* __restrict__ btot,
                                                int* __restrict__ bbase, int nb) {
    __shared__ int tmp[512];
    int t = threadIdx.x;
    int v = (t < nb) ? btot[t] : 0;
    tmp[t] = v;
    __syncthreads();
    for (int off = 1; off < 512; off <<= 1) {
        int u = (t >= off) ? tmp[t - off] : 0;
        __syncthreads();
        tmp[t] += u;
        __syncthreads();
    }
    if (t < nb) bbase[t] = tmp[t] - v;
    if (t == nb - 1) bbase[nb] = tmp[t];
}

__global__ __launch_bounds__(256) void k_bscatter(const int* __restrict__ ei,
                                                  const int* __restrict__ bbase,
                                                  const int* __restrict__ bofs,
                                                  uint32* __restrict__ ebuf,
                                                  int E, int NBUCK, int NCH) {
    __shared__ int cur[512];
    int c = blockIdx.x, tid = threadIdx.x;
    for (int i = tid; i < NBUCK; i += 256)
        cur[i] = bbase[i] + bofs[(size_t)i * NCH + c];
    __syncthreads();
    int base = c * CHUNK;
#pragma unroll
    for (int k = 0; k < CHUNK / 256; ++k) {
        int e = base + k * 256 + tid;
        if (e < E) {
            int s = ei[e];
            int d = ei[E + e];
            int p = atomicAdd(&cur[d >> 8], 1);
            ebuf[p] = (uint32)s | ((uint32)(d & 255) << 20);
        }
    }
}

__global__ __launch_bounds__(256) void k_bsort(const uint32* __restrict__ ebuf,
                                               const int* __restrict__ bbase,
                                               int* __restrict__ ssrc,
                                               int* __restrict__ rowptr,
                                               int* __restrict__ counts,
                                               float* __restrict__ dinv, int N) {
    __shared__ int h[256];
    __shared__ int sc[256];
    __shared__ int cur[256];
    int b = blockIdx.x, tid = threadIdx.x;
    int beg = bbase[b], end = bbase[b + 1];
    h[tid] = 0;
    __syncthreads();
    for (int j = beg + tid; j < end; j += 256)
        atomicAdd(&h[(ebuf[j] >> 20) & 255], 1);
    __syncthreads();
    int v = h[tid];
    sc[tid] = v;
    __syncthreads();
    for (int off = 1; off < 256; off <<= 1) {
        int u = (tid >= off) ? sc[tid - off] : 0;
        __syncthreads();
        sc[tid] += u;
        __syncthreads();
    }
    int rowbase = beg + sc[tid] - v;
    cur[tid] = rowbase;
    int d = b * 256 + tid;
    if (d < N) {
        rowptr[d] = rowbase;
        counts[d] = v;
        dinv[d] = rsqrtf((float)(v + 1));   // +1 self loop
    }
    __syncthreads();
    for (int j = beg + tid; j < end; j += 256) {
        uint32 w = ebuf[j];
        int p = atomicAdd(&cur[(w >> 20) & 255], 1);
        ssrc[p] = (int)(w & 0xFFFFFu);
    }
}

// ============ embed GEMM: h = x @ We^T ([N,128] @ [128,64]^T) ============
// Ws in LDS (stride 129 -> 2-way-free scalar reads). x read via wave-uniform
// global addresses -> compiler promotes to s_load (SMEM pipe), no LDS staging.

__global__ __launch_bounds__(256) void k_embed(const float* __restrict__ x,
                                               const float* __restrict__ We,
                                               float* __restrict__ h, int N) {
    __shared__ float Ws[64 * 129];
    int tid = threadIdx.x;

#pragma unroll
    for (int i = 0; i < 32; ++i) {
        int m = tid + i * 256;
        Ws[(m >> 7) * 129 + (m & 127)] = We[m];
    }
    __syncthreads();

    int f = tid & 63, g = tid >> 6;
    int rbase = blockIdx.x * 32 + g * 8;          // this wave's 8 rows
    const float4* x4 = (const float4*)x;          // row r float4 i at r*32+i

    float acc[8] = {0, 0, 0, 0, 0, 0, 0, 0};
#pragma unroll 4
    for (int k = 0; k < 128; k += 4) {
        float w0 = Ws[f * 129 + k + 0];
        float w1 = Ws[f * 129 + k + 1];
        float w2 = Ws[f * 129 + k + 2];
        float w3 = Ws[f * 129 + k + 3];
#pragma unroll
        for (int j = 0; j < 8; ++j) {
            const float4 xv = x4[(size_t)(rbase + j) * 32 + (k >> 2)];  // wave-uniform
            acc[j] = fmaf(xv.x, w0, acc[j]);
            acc[j] = fmaf(xv.y, w1, acc[j]);
            acc[j] = fmaf(xv.z, w2, acc[j]);
            acc[j] = fmaf(xv.w, w3, acc[j]);
        }
    }
#pragma unroll
    for (int j = 0; j < 8; ++j) {
        h[(size_t)(rbase + j) * 64 + f] = acc[j];
    }
}

// ============ GCN layer GEMM: tab = fp8_e4m3((act(hin) @ Wg^T) * dinv) ============

__global__ __launch_bounds__(256) void k_gcn(const float* __restrict__ hin,
                                             const float* __restrict__ Wg,
                                             const float* __restrict__ bias_prev, int act,
                                             const float* __restrict__ dinv,
                                             uint32* __restrict__ tab, int N) {
    __shared__ float Ws[64 * 65];
    __shared__ float xs[32 * 64];
    int tid = threadIdx.x;

#pragma unroll
    for (int i = 0; i < 16; ++i) {
        int m = tid + i * 256;
        Ws[(m >> 6) * 65 + (m & 63)] = Wg[m];
    }
    int base = blockIdx.x * 32;
    const float4* hin4 = (const float4*)(hin + (size_t)base * 64);
#pragma unroll
    for (int i = 0; i < 2; ++i) {
        int m = tid + i * 256;
        float4 v = hin4[m];
        if (act) {
            int kf = (m & 15) * 4;
            v.x = fmaxf(v.x + bias_prev[kf + 0], 0.f);
            v.y = fmaxf(v.y + bias_prev[kf + 1], 0.f);
            v.z = fmaxf(v.z + bias_prev[kf + 2], 0.f);
            v.w = fmaxf(v.w + bias_prev[kf + 3], 0.f);
        }
        ((float4*)xs)[m] = v;
    }
    __syncthreads();

    int f = tid & 63, g = tid >> 6;
    float acc[8] = {0, 0, 0, 0, 0, 0, 0, 0};
#pragma unroll 4
    for (int k = 0; k < 64; k += 4) {
        float w0 = Ws[f * 65 + k + 0];
        float w1 = Ws[f * 65 + k + 1];
        float w2 = Ws[f * 65 + k + 2];
        float w3 = Ws[f * 65 + k + 3];
#pragma unroll
        for (int j = 0; j < 8; ++j) {
            const float4 xv = *(const float4*)&xs[(g * 8 + j) * 64 + k];
            acc[j] = fmaf(xv.x, w0, acc[j]);
            acc[j] = fmaf(xv.y, w1, acc[j]);
            acc[j] = fmaf(xv.z, w2, acc[j]);
            acc[j] = fmaf(xv.w, w3, acc[j]);
        }
    }

    // epilogue: stage fp32 result back into xs, then pack to fp8
    __syncthreads();
#pragma unroll
    for (int j = 0; j < 8; ++j) {
        int r = g * 8 + j;
        xs[r * 64 + f] = acc[j] * dinv[base + r];
    }
    __syncthreads();
#pragma unroll
    for (int i = 0; i < 2; ++i) {
        int m = tid + i * 256;          // 512 uints = 32 rows x 16
        int row = m >> 4, idx = m & 15;
        const float4 v = *(const float4*)&xs[row * 64 + idx * 4];
        int u = 0;
        u = __builtin_amdgcn_cvt_pk_fp8_f32(v.x, v.y, u, false);
        u = __builtin_amdgcn_cvt_pk_fp8_f32(v.z, v.w, u, true);
        tab[(size_t)(base + row) * 16 + idx] = u;
    }
}

// ============ fp8 CSR gather-aggregate: one wave per dst, 8 edges/gather ============

__global__ __launch_bounds__(256) void k_agg(const int* __restrict__ rowptr,
                                             const int* __restrict__ counts,
                                             const int* __restrict__ ssrc,
                                             const float* __restrict__ dinv,
                                             const uint2* __restrict__ tab2,
                                             float* __restrict__ out, int N) {
    int lane = threadIdx.x & 63;
    int d = blockIdx.x * 4 + (threadIdx.x >> 6);
    if (d >= N) return;
    int q = lane & 7;
    int sub = lane >> 3;
    bool b1 = (sub & 1) != 0, b2 = (sub & 2) != 0, b4 = (sub & 4) != 0;

    float a[8] = {0, 0, 0, 0, 0, 0, 0, 0};
    auto accum = [&](uint2 v) {
        floatx2 f01 = __builtin_amdgcn_cvt_pk_f32_fp8((int)v.x, false);
        floatx2 f23 = __builtin_amdgcn_cvt_pk_f32_fp8((int)v.x, true);
        floatx2 f45 = __builtin_amdgcn_cvt_pk_f32_fp8((int)v.y, false);
        floatx2 f67 = __builtin_amdgcn_cvt_pk_f32_fp8((int)v.y, true);
        a[0] += f01.x; a[1] += f01.y; a[2] += f23.x; a[3] += f23.y;
        a[4] += f45.x; a[5] += f45.y; a[6] += f67.x; a[7] += f67.y;
    };

    if (sub == 0) accum(tab2[(size_t)d * 8 + q]);   // self loop counted once

    int beg = __builtin_amdgcn_readfirstlane(rowptr[d]);
    int cnt = __builtin_amdgcn_readfirstlane(counts[d]);
    const int* srow = ssrc + beg;

#define SEL8(e0,e1,e2,e3,e4,e5,e6,e7) \
    (b4 ? (b2 ? (b1 ? e7 : e6) : (b1 ? e5 : e4)) \
        : (b2 ? (b1 ? e3 : e2) : (b1 ? e1 : e0)))

    int j = 0;
    for (; j + 16 <= cnt; j += 16) {
        int e0 = srow[j + 0],  e1 = srow[j + 1],  e2 = srow[j + 2],  e3 = srow[j + 3];
        int e4 = srow[j + 4],  e5 = srow[j + 5],  e6 = srow[j + 6],  e7 = srow[j + 7];
        int e8 = srow[j + 8],  e9 = srow[j + 9],  ea = srow[j + 10], eb = srow[j + 11];
        int ec = srow[j + 12], ed = srow[j + 13], ee = srow[j + 14], ef = srow[j + 15];
        int t0 = SEL8(e0, e1, e2, e3, e4, e5, e6, e7);
        int t1 = SEL8(e8, e9, ea, eb, ec, ed, ee, ef);
        uint2 v0 = tab2[(size_t)t0 * 8 + q];
        uint2 v1 = tab2[(size_t)t1 * 8 + q];
        accum(v0);
        accum(v1);
    }
    int rem = cnt - j;   // 0..15, wave-uniform
    if (rem) {
        int e0 = srow[j + 0],  e1 = srow[j + 1],  e2 = srow[j + 2],  e3 = srow[j + 3];
        int e4 = srow[j + 4],  e5 = srow[j + 5],  e6 = srow[j + 6],  e7 = srow[j + 7];
        int t0 = SEL8(e0, e1, e2, e3, e4, e5, e6, e7);
        t0 = (sub < rem) ? t0 : N;
        accum(tab2[(size_t)t0 * 8 + q]);
        if (rem > 8) {
            int e8 = srow[j + 8],  e9 = srow[j + 9],  ea = srow[j + 10], eb = srow[j + 11];
            int ec = srow[j + 12], ed = srow[j + 13], ee = srow[j + 14], ef = srow[j + 15];
            int t1 = SEL8(e8, e9, ea, eb, ec, ed, ee, ef);
            t1 = (sub + 8 < rem) ? t1 : N;
            accum(tab2[(size_t)t1 * 8 + q]);
        }
    }
#undef SEL8

#pragma unroll
    for (int i = 0; i < 8; ++i) {
        a[i] += __shfl_xor(a[i], 8);
        a[i] += __shfl_xor(a[i], 16);
        a[i] += __shfl_xor(a[i], 32);
    }

    if (sub == 0) {
        float dd = dinv[d];
        float4* o4 = (float4*)out;
        o4[(size_t)d * 16 + 2 * q + 0] = make_float4(dd * a[0], dd * a[1], dd * a[2], dd * a[3]);
        o4[(size_t)d * 16 + 2 * q + 1] = make_float4(dd * a[4], dd * a[5], dd * a[6], dd * a[7]);
    }
}

// ============ centroid squared norms ============

__global__ void k_c2(const float* __restrict__ C, float* __restrict__ c2) {
    int k = threadIdx.x;
    if (k < 100) {
        float s = 0.f;
        for (int d = 0; d < 64; ++d) { float v = C[k * 64 + d]; s = fmaf(v, v, s); }
        c2[k] = s;
    }
}

// ============ centroid distances + pooling: thread = node, 4 k-groups ============

__global__ __launch_bounds__(256) void k_cent(const float* __restrict__ hin,
                                              const float* __restrict__ b2,
                                              const float* __restrict__ C,
                                              const float* __restrict__ c2g,
                                              float* __restrict__ pooled, int N) {
    __shared__ float pooled_s[32];
    int tid = threadIdx.x;
    int kg = blockIdx.y;                 // 0..3, covers k in [kg*25, kg*25+25)
    if (tid < 32) pooled_s[tid] = 0.f;
    __syncthreads();

    int n = blockIdx.x * 256 + tid;
    bool valid = n < N;

    float h[64];
    float h2 = 0.f;
    {
        const float4* h4 = (const float4*)(hin + ((size_t)(valid ? n : 0) << 6));
#pragma unroll
        for (int i = 0; i < 16; ++i) {
            float4 v = h4[i];
            v.x = fmaxf(v.x + b2[4 * i + 0], 0.f);
            v.y = fmaxf(v.y + b2[4 * i + 1], 0.f);
            v.z = fmaxf(v.z + b2[4 * i + 2], 0.f);
            v.w = fmaxf(v.w + b2[4 * i + 3], 0.f);
            h[4 * i + 0] = v.x; h[4 * i + 1] = v.y;
            h[4 * i + 2] = v.z; h[4 * i + 3] = v.w;
            h2 = fmaf(v.x, v.x, h2); h2 = fmaf(v.y, v.y, h2);
            h2 = fmaf(v.z, v.z, h2); h2 = fmaf(v.w, v.w, h2);
        }
    }

    int kbeg = kg * 25, kend = kbeg + 25;
    for (int k = kbeg; k < kend; ++k) {
        const float* crow = C + k * 64;   // wave-uniform -> scalar loads
        float acc = 0.f;
#pragma unroll
        for (int d = 0; d < 64; ++d) acc = fmaf(h[d], crow[d], acc);
        float d2 = fmaxf(h2 + c2g[k] - 2.f * acc, 0.f);
        float dist = valid ? sqrtf(d2 + 1e-12f) : 0.f;
#pragma unroll
        for (int off = 32; off > 0; off >>= 1) dist += __shfl_xor(dist, off);
        if ((tid & 63) == 0) atomicAdd(&pooled_s[k - kbeg], dist);
    }
    __syncthreads();
    if (tid < 25) atomicAdd(&pooled[kbeg + tid], pooled_s[tid]);
}

// ============ output head ============

__global__ void k_out(const float* __restrict__ pooled,
                      const float* __restrict__ Wout,
                      const float* __restrict__ bout,
                      float* __restrict__ out, float invN) {
    int t = threadIdx.x;
    if (t < 10) {
        float s = 0.f;
        for (int k = 0; k < 100; ++k) s += pooled[k] * Wout[t * 100 + k];
        out[t] = s * invN + bout[t];
    }
}

// ============ launcher ============

extern "C" void kernel_launch(void* const* d_in, const int* in_sizes, int n_in,
                              void* d_out, int out_size, void* d_ws, size_t ws_size,
                              hipStream_t stream) {
    const float* x    = (const float*)d_in[0];
    const int*   ei   = (const int*)d_in[1];
    const float* We   = (const float*)d_in[2];
    const float* Wg   = (const float*)d_in[3];
    const float* bg   = (const float*)d_in[4];
    const float* C    = (const float*)d_in[5];
    const float* Wout = (const float*)d_in[6];
    const float* bout = (const float*)d_in[7];
    float*       out  = (float*)d_out;

    const int N = in_sizes[0] / 128;          // 100000
    const int E = in_sizes[1] / 2;            // 1600000
    const int NBUCK = (N + 255) >> 8;         // 391 dst-buckets
    const int NCH = (E + CHUNK - 1) / CHUNK;  // 98 chunks
    const int NBN = (N + 255) / 256;

    char* ws = (char*)d_ws;
    size_t off = 0;
    auto alloc = [&](size_t bytes) { void* p = ws + off; off += (bytes + 511) & ~(size_t)511; return p; };
    float*  dinv   = (float*)alloc((size_t)N * 4);
    int*    counts = (int*)  alloc((size_t)N * 4);
    int*    rowptr = (int*)  alloc((size_t)N * 4);
    int*    bcnt   = (int*)  alloc((size_t)NBUCK * NCH * 4);
    int*    bofs   = (int*)  alloc((size_t)NBUCK * NCH * 4);
    int*    btot   = (int*)  alloc((size_t)NBUCK * 4);
    int*    bbase  = (int*)  alloc((size_t)(NBUCK + 1) * 4);
    uint32* ebuf   = (uint32*)alloc((size_t)E * 4);
    int*    ssrc   = (int*)  alloc((size_t)(E + 16) * 4);     // +16 pad for agg reads
    float*  hA     = (float*)alloc((size_t)N * 64 * 4);
    uint32* tab    = (uint32*)alloc((size_t)(N + 1) * 64);    // fp8 table + sentinel row
    float*  c2     = (float*)alloc(512);
    float*  pooled = (float*)alloc(512);

    hipMemsetAsync(pooled, 0, 512, stream);
    hipMemsetAsync(tab + (size_t)N * 16, 0, 64, stream);      // sentinel row N = 0

    // bucketed CSR build (no global atomics)
    k_bhist<<<NCH, 256, 0, stream>>>(ei + E, bcnt, E, NBUCK, NCH);
    k_bscan1<<<NBUCK, 128, 0, stream>>>(bcnt, bofs, btot, NCH);
    k_bscan2<<<1, 512, 0, stream>>>(btot, bbase, NBUCK);
    k_bscatter<<<NCH, 256, 0, stream>>>(ei, bbase, bofs, ebuf, E, NBUCK, NCH);
    k_bsort<<<NBUCK, 256, 0, stream>>>(ebuf, bbase, ssrc, rowptr, counts, dinv, N);
    k_c2<<<1, 128, 0, stream>>>(C, c2);

    // embed
    k_embed<<<N / 32, 256, 0, stream>>>(x, We, hA, N);

    // 3 GCN layers: gemm (hA -> fp8 tab, scaled by dinv), aggregate (tab -> hA fp32)
    for (int l = 0; l < 3; ++l) {
        const float* bias_prev = (l == 0) ? bg : (bg + (l - 1) * 64);
        int act = (l == 0) ? 0 : 1;
        k_gcn<<<N / 32, 256, 0, stream>>>(hA, Wg + (size_t)l * 64 * 64, bias_prev, act,
                                          dinv, tab, N);
        k_agg<<<(N + 3) / 4, 256, 0, stream>>>(rowptr, counts, ssrc, dinv,
                                               (const uint2*)tab, hA, N);
    }

    // centroid distances + pooling (applies relu + b_gcn[2]); 4 k-groups
    k_cent<<<dim3(NBN, 4), 256, 0, stream>>>(hA, bg + 2 * 64, C, c2, pooled, N);

    // head
    k_out<<<1, 64, 0, stream>>>(pooled, Wout, bout, out, 1.0f / (float)N);
}